// Round 1
// baseline (709.577 us; speedup 1.0000x reference)
//
#include <hip/hip_runtime.h>
#include <hip/hip_fp16.h>

// GaussianBlur: per-sample-sigma separable depthwise blur, B=64 C=3 H=W=512,
// K=161 (R=80), reflect padding. Strategy:
//   k_weights: per-b padded kernel (176 floats, zeros outside |t|<=80) + radius
//   k_pass1:   vertical blur.  One block per (b,c,x-strip of 64). Whole strip
//              (512x64) staged in LDS as fp16 (64 KB). Sliding 8-reg window,
//              8 outputs/thread. Weights via wave-uniform scalar loads.
//   k_pass2:   horizontal blur. 4 rows/block, LDS rows with pre-reflected halo
//              so inner reads are contiguous 16B ds_read_b128.
// tmp intermediate is fp16 (err ~5e-4 rel << 6.28e-2 threshold); halves HBM.
// ws layout: [0,45056) wpad; [45056,45312) rad; [65536, +100663296) tmp fp16.

#define B_   64
#define C_   3
#define H_   512
#define W_   512
#define R_   80
#define WPAD 176   // 8 zeros | 161 weights | 7 zeros
#define WOFF 88    // wpad index of t=0

__global__ __launch_bounds__(256) void k_weights(const float* __restrict__ sig,
                                                 const int* __restrict__ steps,
                                                 float* __restrict__ wpad,
                                                 int* __restrict__ rad) {
    const int b = blockIdx.x;
    const float sigma = sig[steps[b]] + 1e-6f;
    const int t = (int)threadIdx.x - WOFF;   // [-88, 167]
    float e = 0.f;
    if (t >= -R_ && t <= R_) {
        const float u = (float)t / sigma;
        e = expf(-0.5f * u * u);
    }
    __shared__ float red[256];
    red[threadIdx.x] = e;
    __syncthreads();
    for (int s = 128; s > 0; s >>= 1) {
        if ((int)threadIdx.x < s) red[threadIdx.x] += red[threadIdx.x + s];
        __syncthreads();
    }
    const float inv = 1.0f / red[0];
    if (threadIdx.x < WPAD)
        wpad[b * WPAD + threadIdx.x] = (t >= -R_ && t <= R_) ? e * inv : 0.f;
    if (threadIdx.x == 0) {
        int r = (int)ceilf(6.0f * sigma);   // tail weight < 7e-10
        if (r > R_) r = R_;
        if (r < 1) r = 1;
        rad[b] = r;
    }
}

// ---------------- vertical pass ----------------
__global__ __launch_bounds__(256) void k_pass1(const float* __restrict__ x,
                                               const float* __restrict__ wpad,
                                               const int* __restrict__ rad,
                                               __half* __restrict__ tmp) {
    __shared__ __half sh[H_ * 64];           // 64 KB: [row][col], fp16
    const int tid = threadIdx.x;
    const int bid = blockIdx.x;
    const int bc  = bid >> 3;                // 0..191
    const int xs  = (bid & 7) * 64;
    const int b   = bc / C_;
    const size_t img = (size_t)bc * (H_ * (size_t)W_);

    // stage strip: fp32 -> fp16, float4 loads (each HBM byte read exactly once)
    for (int m = tid; m < H_ * 16; m += 256) {
        const int row = m >> 4, q = m & 15;
        const float4 v = *(const float4*)(x + img + (size_t)row * W_ + xs + q * 4);
        __half2* d = (__half2*)(sh + row * 64 + q * 4);
        d[0] = __floats2half2_rn(v.x, v.y);
        d[1] = __floats2half2_rn(v.z, v.w);
    }
    __syncthreads();

    const int r    = rad[b];                 // wave-uniform
    const int r8   = (r + 7) & ~7;
    const int nblk = (r8 + r + 8) >> 3;
    const float* wb = wpad + b * WPAD + WOFF - r8;
    const int col = tid & 63;
    const int ty  = __builtin_amdgcn_readfirstlane((int)(tid >> 6)); // force sgpr

    for (int c16 = 0; c16 < 16; ++c16) {
        const int row0 = c16 * 32 + ty * 8;
        const int i0   = row0 - r8;
        float acc[8] = {0.f,0.f,0.f,0.f,0.f,0.f,0.f,0.f};
        float Rf[8], Nf[8];
        #pragma unroll
        for (int m = 0; m < 8; ++m) {
            int i = i0 + m;
            int ri = i < 0 ? -i : i;
            ri = ri > (H_ - 1) ? 2 * (H_ - 1) - ri : ri;
            Rf[m] = __half2float(sh[ri * 64 + col]);
        }
        for (int blk = 0; blk < nblk; ++blk) {
            const int ib = i0 + (blk + 1) * 8;
            #pragma unroll
            for (int m = 0; m < 8; ++m) {
                int i = ib + m;
                int ri = i < 0 ? -i : i;
                ri = ri > (H_ - 1) ? 2 * (H_ - 1) - ri : ri;
                Nf[m] = __half2float(sh[ri * 64 + col]);
            }
            const float* wt = wb + blk * 8;  // all-sgpr address -> s_load
            #pragma unroll
            for (int k = 0; k < 8; ++k) {
                const float wv = wt[k];
                #pragma unroll
                for (int j = 0; j < 8; ++j) {
                    const float vv = (k + j < 8) ? Rf[k + j] : Nf[k + j - 8];
                    acc[j] = fmaf(wv, vv, acc[j]);
                }
            }
            #pragma unroll
            for (int m = 0; m < 8; ++m) Rf[m] = Nf[m];
        }
        #pragma unroll
        for (int j = 0; j < 8; ++j)
            tmp[img + (size_t)(row0 + j) * W_ + xs + col] = __float2half_rn(acc[j]);
    }
}

// ---------------- horizontal pass ----------------
#define P2S 704   // LDS row stride in halfs (688 used: 88 | 512 | 88)

__global__ __launch_bounds__(256) void k_pass2(const __half* __restrict__ tmp,
                                               const float* __restrict__ wpad,
                                               const int* __restrict__ rad,
                                               float* __restrict__ out) {
    __shared__ __half sh[4 * P2S];
    const int tid = threadIdx.x;
    const int bid = blockIdx.x;
    const int bc  = bid >> 7;
    const int y0  = (bid & 127) * 4;
    const int b   = bc / C_;
    const size_t base = ((size_t)bc * H_ + y0) * (size_t)W_;

    // body: 4 rows x 64 uint4 (one per thread)
    {
        const int row = tid >> 6, q = tid & 63;
        const uint4 v = *(const uint4*)(tmp + base + (size_t)row * W_ + q * 8);
        *(uint4*)(sh + row * P2S + 88 + q * 8) = v;
    }
    // pre-reflected halo (88 each side)
    for (int m = tid; m < 4 * 176; m += 256) {
        const int row = m / 176, e = m - row * 176;
        const int d = e < 88 ? e : e + 512;
        const int xx = d - 88;
        const int rx = xx < 0 ? -xx : (xx > (W_ - 1) ? 2 * (W_ - 1) - xx : xx);
        sh[row * P2S + d] = tmp[base + (size_t)row * W_ + rx];
    }
    __syncthreads();

    const int r    = rad[b];
    const int r8   = (r + 7) & ~7;
    const int nblk = (r8 + r + 8) >> 3;
    const float* wb = wpad + b * WPAD + WOFF - r8;
    const int row = tid >> 6;
    const int xq  = tid & 63;
    const int p0  = row * P2S + 88 + xq * 8 - r8;   // 16B-aligned half index

    float acc[8] = {0.f,0.f,0.f,0.f,0.f,0.f,0.f,0.f};
    float Rf[8], Nf[8];
    {
        const uint4 v = *(const uint4*)(sh + p0);
        const __half* hp = (const __half*)&v;
        #pragma unroll
        for (int m = 0; m < 8; ++m) Rf[m] = __half2float(hp[m]);
    }
    for (int blk = 0; blk < nblk; ++blk) {
        const uint4 v = *(const uint4*)(sh + p0 + (blk + 1) * 8);
        const __half* hp = (const __half*)&v;
        #pragma unroll
        for (int m = 0; m < 8; ++m) Nf[m] = __half2float(hp[m]);
        const float* wt = wb + blk * 8;
        #pragma unroll
        for (int k = 0; k < 8; ++k) {
            const float wv = wt[k];
            #pragma unroll
            for (int j = 0; j < 8; ++j) {
                const float vv = (k + j < 8) ? Rf[k + j] : Nf[k + j - 8];
                acc[j] = fmaf(wv, vv, acc[j]);
            }
        }
        #pragma unroll
        for (int m = 0; m < 8; ++m) Rf[m] = Nf[m];
    }
    const size_t o = base + (size_t)row * W_ + (size_t)xq * 8;
    *(float4*)(out + o)     = make_float4(acc[0], acc[1], acc[2], acc[3]);
    *(float4*)(out + o + 4) = make_float4(acc[4], acc[5], acc[6], acc[7]);
}

extern "C" void kernel_launch(void* const* d_in, const int* in_sizes, int n_in,
                              void* d_out, int out_size, void* d_ws, size_t ws_size,
                              hipStream_t stream) {
    const float* x     = (const float*)d_in[0];
    const float* sig   = (const float*)d_in[1];
    const int*   steps = (const int*)d_in[2];
    float* out = (float*)d_out;

    char* ws = (char*)d_ws;
    float* wpad = (float*)ws;                       // 45056 B
    int*   rad  = (int*)(ws + 45056);               // 256 B
    __half* tmp = (__half*)(ws + 65536);            // 100663296 B (needs ws >= ~100.8 MB)

    k_weights<<<B_, 256, 0, stream>>>(sig, steps, wpad, rad);
    k_pass1<<<B_ * C_ * (W_ / 64), 256, 0, stream>>>(x, wpad, rad, tmp);
    k_pass2<<<B_ * C_ * (H_ / 4), 256, 0, stream>>>(tmp, wpad, rad, out);
}

// Round 2
// 507.931 us; speedup vs baseline: 1.3970x; 1.3970x over previous
//
#include <hip/hip_runtime.h>
#include <hip/hip_fp16.h>

// GaussianBlur: per-sample-sigma separable depthwise blur, B=64 C=3 H=W=512,
// K=161 (R=80), reflect padding.
// R2: pass1 = y-chunked (128 rows) with pre-reflected halo staged in LDS
//     (40 KB -> 4 blocks/CU), half2 column-pair inner loop, float2 accum
//     (__builtin_elementwise_fma -> v_pk_fma_f32). No reflect math inner.
//     pass2 = 8 rows/block, 2 independent row-windows per thread (2x ILP).
// ws layout: [0,45056) wpad; [45056,45312) rad; [65536, +100663296) tmp fp16.

#define B_   64
#define C_   3
#define H_   512
#define W_   512
#define R_   80
#define WPAD 176   // 8 zeros | 161 weights | 7 zeros
#define WOFF 88    // wpad index of t=0

typedef float f32x2 __attribute__((ext_vector_type(2)));

__global__ __launch_bounds__(256) void k_weights(const float* __restrict__ sig,
                                                 const int* __restrict__ steps,
                                                 float* __restrict__ wpad,
                                                 int* __restrict__ rad) {
    const int b = blockIdx.x;
    const float sigma = sig[steps[b]] + 1e-6f;
    const int t = (int)threadIdx.x - WOFF;   // [-88, 167]
    float e = 0.f;
    if (t >= -R_ && t <= R_) {
        const float u = (float)t / sigma;
        e = expf(-0.5f * u * u);
    }
    __shared__ float red[256];
    red[threadIdx.x] = e;
    __syncthreads();
    for (int s = 128; s > 0; s >>= 1) {
        if ((int)threadIdx.x < s) red[threadIdx.x] += red[threadIdx.x + s];
        __syncthreads();
    }
    const float inv = 1.0f / red[0];
    if (threadIdx.x < WPAD)
        wpad[b * WPAD + threadIdx.x] = (t >= -R_ && t <= R_) ? e * inv : 0.f;
    if (threadIdx.x == 0) {
        int r = (int)ceilf(6.0f * sigma);   // tail weight < 7e-10
        if (r > R_) r = R_;
        if (r < 1) r = 1;
        rad[b] = r;
    }
}

// ---------------- vertical pass ----------------
// block: (bc, 64-wide x-strip, 128-row y-chunk). LDS holds local rows
// 0..303 = global rows [y0-80, y0+223], pre-reflected. Stride 66 halfs
// (pad +2: conflict-free for both staging writes and half2 reads).
#define P1R  304
#define P1S  66

__global__ __launch_bounds__(256) void k_pass1(const float* __restrict__ x,
                                               const float* __restrict__ wpad,
                                               const int* __restrict__ rad,
                                               __half* __restrict__ tmp) {
    __shared__ __half sh[P1R * P1S];         // 40128 B -> 4 blocks/CU
    const int tid = threadIdx.x;
    const int bid = blockIdx.x;
    const int bc  = bid >> 5;                // 0..191
    const int rem = bid & 31;
    const int xs  = (rem & 7) << 6;          // x-strip start
    const int y0  = (rem >> 3) << 7;         // y-chunk start
    const int b   = bc / C_;
    const size_t img = (size_t)bc * (H_ * (size_t)W_);
    const int ystart = y0 - 80;

    // stage 304 rows x 64 cols, reflected at staging (only time reflect runs)
    for (int m = tid; m < P1R * 16; m += 256) {
        const int row = m >> 4, q = m & 15;
        int gy = ystart + row;               // [-80, 607]
        gy = gy < 0 ? -gy : gy;
        gy = gy > (H_ - 1) ? 2 * (H_ - 1) - gy : gy;
        const float4 v = *(const float4*)(x + img + (size_t)gy * W_ + xs + q * 4);
        __half2* d = (__half2*)(sh + row * P1S + q * 4);
        d[0] = __floats2half2_rn(v.x, v.y);
        d[1] = __floats2half2_rn(v.z, v.w);
    }
    __syncthreads();

    const int r    = rad[b];                 // block-uniform -> sgpr
    const int r8   = (r + 7) & ~7;
    const int nblk = (r8 + r + 8) >> 3;
    const float* wb = wpad + b * WPAD + WOFF - r8;
    const int cp  = tid & 31;                // column pair 0..31
    const int ty  = tid >> 5;                // 0..7
    const int col0 = cp * 2;

    #pragma unroll
    for (int g = 0; g < 2; ++g) {
        const int L0 = ty * 16 + g * 8 + 80; // local row of first output
        const int i0 = L0 - r8;              // >= 0
        f32x2 acc[8];
        #pragma unroll
        for (int j = 0; j < 8; ++j) acc[j] = (f32x2){0.f, 0.f};
        f32x2 Rf[8], Nf[8];
        #pragma unroll
        for (int m = 0; m < 8; ++m) {
            const __half2 h = *(const __half2*)(sh + (i0 + m) * P1S + col0);
            Rf[m] = (f32x2){__low2float(h), __high2float(h)};
        }
        for (int blk = 0; blk < nblk; ++blk) {
            const int ib = i0 + (blk + 1) * 8;
            #pragma unroll
            for (int m = 0; m < 8; ++m) {
                const __half2 h = *(const __half2*)(sh + (ib + m) * P1S + col0);
                Nf[m] = (f32x2){__low2float(h), __high2float(h)};
            }
            const float* wt = wb + blk * 8;  // uniform -> s_load
            #pragma unroll
            for (int k = 0; k < 8; ++k) {
                const float w = wt[k];
                const f32x2 w2 = {w, w};
                #pragma unroll
                for (int j = 0; j < 8; ++j) {
                    const f32x2 vv = (k + j < 8) ? Rf[k + j] : Nf[k + j - 8];
                    acc[j] = __builtin_elementwise_fma(w2, vv, acc[j]);
                }
            }
            #pragma unroll
            for (int m = 0; m < 8; ++m) Rf[m] = Nf[m];
        }
        const int gy0 = y0 + ty * 16 + g * 8;
        #pragma unroll
        for (int j = 0; j < 8; ++j) {
            *(__half2*)(tmp + img + (size_t)(gy0 + j) * W_ + xs + col0) =
                __floats2half2_rn(acc[j].x, acc[j].y);
        }
    }
}

// ---------------- horizontal pass ----------------
#define P2S 704   // LDS row stride in halfs (688 used: 88 | 512 | 88)

__global__ __launch_bounds__(256) void k_pass2(const __half* __restrict__ tmp,
                                               const float* __restrict__ wpad,
                                               const int* __restrict__ rad,
                                               float* __restrict__ out) {
    __shared__ __half sh[8 * P2S];           // 11264 B
    const int tid = threadIdx.x;
    const int bid = blockIdx.x;
    const int bc  = bid >> 6;
    const int y0  = (bid & 63) * 8;
    const int b   = bc / C_;
    const size_t base = ((size_t)bc * H_ + y0) * (size_t)W_;

    // body: 8 rows x 64 uint4
    #pragma unroll
    for (int it = 0; it < 2; ++it) {
        const int m = tid + it * 256;
        const int row = m >> 6, q = m & 63;
        const uint4 v = *(const uint4*)(tmp + base + (size_t)row * W_ + q * 8);
        *(uint4*)(sh + row * P2S + 88 + q * 8) = v;
    }
    // pre-reflected halo (88 each side)
    for (int m = tid; m < 8 * 176; m += 256) {
        const int row = m / 176, e = m - row * 176;
        const int d = e < 88 ? e : e + 512;
        const int xx = d - 88;
        const int rx = xx < 0 ? -xx : (xx > (W_ - 1) ? 2 * (W_ - 1) - xx : xx);
        sh[row * P2S + d] = tmp[base + (size_t)row * W_ + rx];
    }
    __syncthreads();

    const int r    = rad[b];
    const int r8   = (r + 7) & ~7;
    const int nblk = (r8 + r + 8) >> 3;
    const float* wb = wpad + b * WPAD + WOFF - r8;
    const int rw  = tid >> 6;                // handles rows rw and rw+4
    const int xq  = tid & 63;
    const int p0a = rw * P2S + 88 + xq * 8 - r8;
    const int p0b = (rw + 4) * P2S + 88 + xq * 8 - r8;

    float accA[8] = {0,0,0,0,0,0,0,0}, accB[8] = {0,0,0,0,0,0,0,0};
    float RfA[8], NfA[8], RfB[8], NfB[8];
    {
        const uint4 va = *(const uint4*)(sh + p0a);
        const uint4 vb = *(const uint4*)(sh + p0b);
        const __half* ha = (const __half*)&va;
        const __half* hb = (const __half*)&vb;
        #pragma unroll
        for (int m = 0; m < 8; ++m) { RfA[m] = __half2float(ha[m]); RfB[m] = __half2float(hb[m]); }
    }
    for (int blk = 0; blk < nblk; ++blk) {
        const uint4 va = *(const uint4*)(sh + p0a + (blk + 1) * 8);
        const uint4 vb = *(const uint4*)(sh + p0b + (blk + 1) * 8);
        const __half* ha = (const __half*)&va;
        const __half* hb = (const __half*)&vb;
        #pragma unroll
        for (int m = 0; m < 8; ++m) { NfA[m] = __half2float(ha[m]); NfB[m] = __half2float(hb[m]); }
        const float* wt = wb + blk * 8;
        #pragma unroll
        for (int k = 0; k < 8; ++k) {
            const float w = wt[k];
            #pragma unroll
            for (int j = 0; j < 8; ++j) {
                const float vA = (k + j < 8) ? RfA[k + j] : NfA[k + j - 8];
                const float vB = (k + j < 8) ? RfB[k + j] : NfB[k + j - 8];
                accA[j] = fmaf(w, vA, accA[j]);
                accB[j] = fmaf(w, vB, accB[j]);
            }
        }
        #pragma unroll
        for (int m = 0; m < 8; ++m) { RfA[m] = NfA[m]; RfB[m] = NfB[m]; }
    }
    const size_t oa = base + (size_t)rw * W_ + (size_t)xq * 8;
    const size_t ob = base + (size_t)(rw + 4) * W_ + (size_t)xq * 8;
    *(float4*)(out + oa)     = make_float4(accA[0], accA[1], accA[2], accA[3]);
    *(float4*)(out + oa + 4) = make_float4(accA[4], accA[5], accA[6], accA[7]);
    *(float4*)(out + ob)     = make_float4(accB[0], accB[1], accB[2], accB[3]);
    *(float4*)(out + ob + 4) = make_float4(accB[4], accB[5], accB[6], accB[7]);
}

extern "C" void kernel_launch(void* const* d_in, const int* in_sizes, int n_in,
                              void* d_out, int out_size, void* d_ws, size_t ws_size,
                              hipStream_t stream) {
    const float* x     = (const float*)d_in[0];
    const float* sig   = (const float*)d_in[1];
    const int*   steps = (const int*)d_in[2];
    float* out = (float*)d_out;

    char* ws = (char*)d_ws;
    float* wpad = (float*)ws;                       // 45056 B
    int*   rad  = (int*)(ws + 45056);               // 256 B
    __half* tmp = (__half*)(ws + 65536);            // 100663296 B

    k_weights<<<B_, 256, 0, stream>>>(sig, steps, wpad, rad);
    k_pass1<<<B_ * C_ * 8 * 4, 256, 0, stream>>>(x, wpad, rad, tmp);
    k_pass2<<<B_ * C_ * (H_ / 8), 256, 0, stream>>>(tmp, wpad, rad, out);
}